// Round 1
// baseline (118.521 us; speedup 1.0000x reference)
//
#include <hip/hip_runtime.h>

#define NPTS 2048
#define CSEG 256
#define HARD_COS 0.9914448613738104f  // cos(7.5 deg); ang>15deg <=> clipped |dot| < this

// ws layout per sample (stride 24 floats): [0..8]=R_pred, [9..17]=R_gt,
// [18]=cls, [19]=valid, [20]=use_closest
__global__ void pm_prep(const float* __restrict__ pred,
                        const float* __restrict__ tgt,
                        const float* __restrict__ wgt,
                        const float* __restrict__ sym,
                        float* __restrict__ ws,
                        float* __restrict__ out,
                        int B, int C) {
    int b = blockIdx.x * blockDim.x + threadIdx.x;
    if (b == 0) out[0] = 0.0f;   // harness poisons d_out; loss kernel atomically adds
    if (b >= B) return;

    int cls = 0; float valid = 0.0f;
    for (int c = 0; c < C; ++c) {
        if (wgt[b * 4 * C + c * 4] > 0.0f) { cls = c; valid = 1.0f; break; }
    }
    const float* qp = pred + b * 4 * C + cls * 4;
    const float* qg = tgt  + b * 4 * C + cls * 4;
    float pw = qp[0], px = qp[1], py = qp[2], pz = qp[3];
    float gw = qg[0], gx = qg[1], gy = qg[2], gz = qg[3];

    float* o = ws + (size_t)b * 24;
    // R_pred
    o[0] = 1.f - 2.f * (py * py + pz * pz);
    o[1] = 2.f * (px * py - pz * pw);
    o[2] = 2.f * (px * pz + py * pw);
    o[3] = 2.f * (px * py + pz * pw);
    o[4] = 1.f - 2.f * (px * px + pz * pz);
    o[5] = 2.f * (py * pz - px * pw);
    o[6] = 2.f * (px * pz - py * pw);
    o[7] = 2.f * (py * pz + px * pw);
    o[8] = 1.f - 2.f * (px * px + py * py);
    // R_gt
    o[9]  = 1.f - 2.f * (gy * gy + gz * gz);
    o[10] = 2.f * (gx * gy - gz * gw);
    o[11] = 2.f * (gx * gz + gy * gw);
    o[12] = 2.f * (gx * gy + gz * gw);
    o[13] = 1.f - 2.f * (gx * gx + gz * gz);
    o[14] = 2.f * (gy * gz - gx * gw);
    o[15] = 2.f * (gx * gz - gy * gw);
    o[16] = 2.f * (gy * gz + gx * gw);
    o[17] = 1.f - 2.f * (gx * gx + gy * gy);

    float dot = fabsf(pw * gw + px * gx + py * gy + pz * gz);
    dot = fminf(fmaxf(dot, 0.0f), 1.0f);
    float uc = (sym[cls] > 0.0f && dot < HARD_COS) ? 1.0f : 0.0f;
    o[18] = (float)cls;
    o[19] = valid;
    o[20] = uc;
}

__device__ __forceinline__ float smooth_l1(float x) {
    float ax = fabsf(x);
    return (ax < 1.0f) ? 0.5f * x * x : ax - 0.5f;
}

__global__ __launch_bounds__(256) void pm_loss(const float* __restrict__ points,
                                               const float* __restrict__ ws,
                                               float* __restrict__ out,
                                               float inv_bp) {
    __shared__ float4 gt[NPTS];        // {x, y, z, |g|^2}
    __shared__ float partial[4];

    const int b = blockIdx.y;
    const float* o = ws + (size_t)b * 24;
    const float r0 = o[0], r1 = o[1], r2 = o[2],
                r3 = o[3], r4 = o[4], r5 = o[5],
                r6 = o[6], r7 = o[7], r8 = o[8];
    const float g0 = o[9],  g1 = o[10], g2 = o[11],
                g3 = o[12], g4 = o[13], g5 = o[14],
                g6 = o[15], g7 = o[16], g8 = o[17];
    const int   cls = (int)o[18];
    const float valid = o[19];
    const bool  uc = o[20] > 0.5f;

    const float* pts = points + (size_t)cls * NPTS * 3;
    const int tid = threadIdx.x;

    // stage rotated gt points into LDS (SoA-in-float4 for broadcast b128 reads)
    for (int i = tid; i < NPTS; i += 256) {
        float x = pts[i * 3 + 0], y = pts[i * 3 + 1], z = pts[i * 3 + 2];
        float ax = g0 * x + g1 * y + g2 * z;
        float ay = g3 * x + g4 * y + g5 * z;
        float az = g6 * x + g7 * y + g8 * z;
        gt[i] = make_float4(ax, ay, az, ax * ax + ay * ay + az * az);
    }
    __syncthreads();

    const int p = blockIdx.x * CSEG + tid;
    float x = pts[p * 3 + 0], y = pts[p * 3 + 1], z = pts[p * 3 + 2];
    const float ppx = r0 * x + r1 * y + r2 * z;
    const float ppy = r3 * x + r4 * y + r5 * z;
    const float ppz = r6 * x + r7 * y + r8 * z;

    float mx, my, mz;
    if (uc) {
        // argmin_q |pp - gt_q|^2 ; drop constant |pp|^2, scan d = |g|^2 - 2 pp.g
        const float nx = -2.0f * ppx, ny = -2.0f * ppy, nz = -2.0f * ppz;
        float best = 3.4e38f;
        int bq = 0;
        for (int q = 0; q < NPTS; ++q) {
            float4 g = gt[q];
            float d = __fmaf_rn(nx, g.x, __fmaf_rn(ny, g.y, __fmaf_rn(nz, g.z, g.w)));
            if (d < best) { best = d; bq = q; }   // strict <: first min, matches argmin
        }
        float4 g = gt[bq];
        mx = g.x; my = g.y; mz = g.z;
    } else {
        float4 g = gt[p];
        mx = g.x; my = g.y; mz = g.z;
    }

    float acc = smooth_l1(ppx - mx) + smooth_l1(ppy - my) + smooth_l1(ppz - mz);
    acc *= valid;

    // wave (64) reduce, then cross-wave via LDS
    for (int off = 32; off > 0; off >>= 1) acc += __shfl_down(acc, off);
    if ((tid & 63) == 0) partial[tid >> 6] = acc;
    __syncthreads();
    if (tid == 0) {
        float s = partial[0] + partial[1] + partial[2] + partial[3];
        atomicAdd(out, s * inv_bp);
    }
}

extern "C" void kernel_launch(void* const* d_in, const int* in_sizes, int n_in,
                              void* d_out, int out_size, void* d_ws, size_t ws_size,
                              hipStream_t stream) {
    const float* pred = (const float*)d_in[0];
    const float* tgt  = (const float*)d_in[1];
    const float* wgt  = (const float*)d_in[2];
    const float* pts  = (const float*)d_in[3];
    const float* sym  = (const float*)d_in[4];
    float* out = (float*)d_out;
    float* ws  = (float*)d_ws;

    const int C = in_sizes[4];
    const int B = in_sizes[0] / (4 * C);

    pm_prep<<<1, 64, 0, stream>>>(pred, tgt, wgt, sym, ws, out, B, C);
    dim3 grid(NPTS / CSEG, B);
    pm_loss<<<grid, 256, 0, stream>>>(pts, ws, out, 1.0f / (float)(B * NPTS));
}

// Round 2
// 97.506 us; speedup vs baseline: 1.2155x; 1.2155x over previous
//
#include <hip/hip_runtime.h>

#define NPTS 2048
#define QC 8                    // q-chunks per sample
#define QLEN (NPTS / QC)        // 256 gt points per chunk
#define HARD_COS 0.9914448613738104f  // cos(7.5 deg); ang>15deg <=> clipped |dot| < this
#define META_FLOATS 24
#define PART_OFFSET (32 * META_FLOATS)   // floats; 16B-aligned (3072 B)

// ws meta layout per sample (stride 24 floats): [0..8]=R_pred, [9..17]=R_gt,
// [18]=cls, [19]=valid, [20]=use_closest
// ws partials at float offset PART_OFFSET: [b][p][qc] = best q index (as float)
__global__ void pm_prep(const float* __restrict__ pred,
                        const float* __restrict__ tgt,
                        const float* __restrict__ wgt,
                        const float* __restrict__ sym,
                        float* __restrict__ ws,
                        float* __restrict__ out,
                        int B, int C) {
    int b = blockIdx.x * blockDim.x + threadIdx.x;
    if (b == 0) out[0] = 0.0f;   // harness poisons d_out; final kernel atomically adds
    if (b >= B) return;

    int cls = 0; float valid = 0.0f;
    for (int c = 0; c < C; ++c) {
        if (wgt[b * 4 * C + c * 4] > 0.0f) { cls = c; valid = 1.0f; break; }
    }
    const float* qp = pred + b * 4 * C + cls * 4;
    const float* qg = tgt  + b * 4 * C + cls * 4;
    float pw = qp[0], px = qp[1], py = qp[2], pz = qp[3];
    float gw = qg[0], gx = qg[1], gy = qg[2], gz = qg[3];

    float* o = ws + (size_t)b * META_FLOATS;
    o[0] = 1.f - 2.f * (py * py + pz * pz);
    o[1] = 2.f * (px * py - pz * pw);
    o[2] = 2.f * (px * pz + py * pw);
    o[3] = 2.f * (px * py + pz * pw);
    o[4] = 1.f - 2.f * (px * px + pz * pz);
    o[5] = 2.f * (py * pz - px * pw);
    o[6] = 2.f * (px * pz - py * pw);
    o[7] = 2.f * (py * pz + px * pw);
    o[8] = 1.f - 2.f * (px * px + py * py);
    o[9]  = 1.f - 2.f * (gy * gy + gz * gz);
    o[10] = 2.f * (gx * gy - gz * gw);
    o[11] = 2.f * (gx * gz + gy * gw);
    o[12] = 2.f * (gx * gy + gz * gw);
    o[13] = 1.f - 2.f * (gx * gx + gz * gz);
    o[14] = 2.f * (gy * gz - gx * gw);
    o[15] = 2.f * (gx * gz - gy * gw);
    o[16] = 2.f * (gy * gz + gx * gw);
    o[17] = 1.f - 2.f * (gx * gx + gy * gy);

    float dot = fabsf(pw * gw + px * gx + py * gy + pz * gz);
    dot = fminf(fmaxf(dot, 0.0f), 1.0f);
    float uc = (sym[cls] > 0.0f && dot < HARD_COS) ? 1.0f : 0.0f;
    o[18] = (float)cls;
    o[19] = valid;
    o[20] = uc;
}

__device__ __forceinline__ float smooth_l1(float x) {
    float ax = fabsf(x);
    return (ax < 1.0f) ? 0.5f * x * x : ax - 0.5f;
}

// One block per (pred-segment, sample, q-chunk). Finds, for each of its 256
// pred points, the argmin over this chunk's 256 gt points.
__global__ __launch_bounds__(256) void pm_partial(const float* __restrict__ points,
                                                  float* __restrict__ ws) {
    const int b  = blockIdx.y;
    const int qc = blockIdx.z;
    const float* o = ws + (size_t)b * META_FLOATS;
    if (o[19] == 0.0f || o[20] == 0.0f) return;   // !valid or !use_closest

    const float r0 = o[0], r1 = o[1], r2 = o[2],
                r3 = o[3], r4 = o[4], r5 = o[5],
                r6 = o[6], r7 = o[7], r8 = o[8];
    const float g0 = o[9],  g1 = o[10], g2 = o[11],
                g3 = o[12], g4 = o[13], g5 = o[14],
                g6 = o[15], g7 = o[16], g8 = o[17];
    const int cls = (int)o[18];
    const float* pts = points + (size_t)cls * NPTS * 3;
    const int tid = threadIdx.x;
    const int qbase = qc * QLEN;

    __shared__ float4 gt[QLEN];   // {x, y, z, |g|^2}
    {
        int i = tid;  // QLEN == 256 == blockDim.x
        float x = pts[(qbase + i) * 3 + 0];
        float y = pts[(qbase + i) * 3 + 1];
        float z = pts[(qbase + i) * 3 + 2];
        float ax = g0 * x + g1 * y + g2 * z;
        float ay = g3 * x + g4 * y + g5 * z;
        float az = g6 * x + g7 * y + g8 * z;
        gt[i] = make_float4(ax, ay, az, ax * ax + ay * ay + az * az);
    }
    __syncthreads();

    const int p = blockIdx.x * 256 + tid;
    float x = pts[p * 3 + 0], y = pts[p * 3 + 1], z = pts[p * 3 + 2];
    const float ppx = r0 * x + r1 * y + r2 * z;
    const float ppy = r3 * x + r4 * y + r5 * z;
    const float ppz = r6 * x + r7 * y + r8 * z;
    const float nx = -2.0f * ppx, ny = -2.0f * ppy, nz = -2.0f * ppz;

    // 4 independent min-chains (q = 4k+j) for ILP; lexicographic combine keeps
    // exact first-min semantics.
    float b0 = 3.4e38f, b1 = 3.4e38f, b2 = 3.4e38f, b3 = 3.4e38f;
    int   i0 = 0, i1 = 0, i2 = 0, i3 = 0;
#pragma unroll 8
    for (int k = 0; k < QLEN / 4; ++k) {
        float4 ga = gt[4 * k + 0];
        float4 gb = gt[4 * k + 1];
        float4 gc = gt[4 * k + 2];
        float4 gd = gt[4 * k + 3];
        float d0 = __fmaf_rn(nx, ga.x, __fmaf_rn(ny, ga.y, __fmaf_rn(nz, ga.z, ga.w)));
        float d1 = __fmaf_rn(nx, gb.x, __fmaf_rn(ny, gb.y, __fmaf_rn(nz, gb.z, gb.w)));
        float d2 = __fmaf_rn(nx, gc.x, __fmaf_rn(ny, gc.y, __fmaf_rn(nz, gc.z, gc.w)));
        float d3 = __fmaf_rn(nx, gd.x, __fmaf_rn(ny, gd.y, __fmaf_rn(nz, gd.z, gd.w)));
        if (d0 < b0) { b0 = d0; i0 = 4 * k + 0; }
        if (d1 < b1) { b1 = d1; i1 = 4 * k + 1; }
        if (d2 < b2) { b2 = d2; i2 = 4 * k + 2; }
        if (d3 < b3) { b3 = d3; i3 = 4 * k + 3; }
    }
    float bd = b0; int bi = i0;
    if (b1 < bd || (b1 == bd && i1 < bi)) { bd = b1; bi = i1; }
    if (b2 < bd || (b2 == bd && i2 < bi)) { bd = b2; bi = i2; }
    if (b3 < bd || (b3 == bd && i3 < bi)) { bd = b3; bi = i3; }

    ws[PART_OFFSET + ((size_t)b * NPTS + p) * QC + qc] = (float)(qbase + bi);
}

// One block per (pred-segment, sample): resolve the QC chunk winners,
// compute smooth-L1, reduce, atomicAdd.
__global__ __launch_bounds__(256) void pm_final(const float* __restrict__ points,
                                                const float* __restrict__ ws,
                                                float* __restrict__ out,
                                                float inv_bp) {
    __shared__ float partial[4];
    const int b = blockIdx.y;
    const float* o = ws + (size_t)b * META_FLOATS;
    const float valid = o[19];
    const int tid = threadIdx.x;
    float acc = 0.0f;

    if (valid != 0.0f) {
        const float r0 = o[0], r1 = o[1], r2 = o[2],
                    r3 = o[3], r4 = o[4], r5 = o[5],
                    r6 = o[6], r7 = o[7], r8 = o[8];
        const float g0 = o[9],  g1 = o[10], g2 = o[11],
                    g3 = o[12], g4 = o[13], g5 = o[14],
                    g6 = o[15], g7 = o[16], g8 = o[17];
        const int cls = (int)o[18];
        const bool uc = o[20] != 0.0f;
        const float* pts = points + (size_t)cls * NPTS * 3;
        const int p = blockIdx.x * 256 + tid;

        float x = pts[p * 3 + 0], y = pts[p * 3 + 1], z = pts[p * 3 + 2];
        const float ppx = r0 * x + r1 * y + r2 * z;
        const float ppy = r3 * x + r4 * y + r5 * z;
        const float ppz = r6 * x + r7 * y + r8 * z;

        float mx, my, mz;
        if (uc) {
            const float nx = -2.0f * ppx, ny = -2.0f * ppy, nz = -2.0f * ppz;
            const float* cand = ws + PART_OFFSET + ((size_t)b * NPTS + p) * QC;
            float bd = 3.4e38f; mx = 0.f; my = 0.f; mz = 0.f;
#pragma unroll
            for (int c = 0; c < QC; ++c) {   // candidates are in ascending-q order
                int q = (int)cand[c];
                float qx = pts[q * 3 + 0], qy = pts[q * 3 + 1], qz = pts[q * 3 + 2];
                float ax = g0 * qx + g1 * qy + g2 * qz;
                float ay = g3 * qx + g4 * qy + g5 * qz;
                float az = g6 * qx + g7 * qy + g8 * qz;
                float w = ax * ax + ay * ay + az * az;
                float d = __fmaf_rn(nx, ax, __fmaf_rn(ny, ay, __fmaf_rn(nz, az, w)));
                if (d < bd) { bd = d; mx = ax; my = ay; mz = az; }
            }
        } else {
            mx = g0 * x + g1 * y + g2 * z;
            my = g3 * x + g4 * y + g5 * z;
            mz = g6 * x + g7 * y + g8 * z;
        }
        acc = smooth_l1(ppx - mx) + smooth_l1(ppy - my) + smooth_l1(ppz - mz);
    }

    for (int off = 32; off > 0; off >>= 1) acc += __shfl_down(acc, off);
    if ((tid & 63) == 0) partial[tid >> 6] = acc;
    __syncthreads();
    if (tid == 0) {
        float s = partial[0] + partial[1] + partial[2] + partial[3];
        atomicAdd(out, s * inv_bp);
    }
}

extern "C" void kernel_launch(void* const* d_in, const int* in_sizes, int n_in,
                              void* d_out, int out_size, void* d_ws, size_t ws_size,
                              hipStream_t stream) {
    const float* pred = (const float*)d_in[0];
    const float* tgt  = (const float*)d_in[1];
    const float* wgt  = (const float*)d_in[2];
    const float* pts  = (const float*)d_in[3];
    const float* sym  = (const float*)d_in[4];
    float* out = (float*)d_out;
    float* ws  = (float*)d_ws;

    const int C = in_sizes[4];
    const int B = in_sizes[0] / (4 * C);

    pm_prep<<<1, 64, 0, stream>>>(pred, tgt, wgt, sym, ws, out, B, C);
    dim3 gridP(NPTS / 256, B, QC);
    pm_partial<<<gridP, 256, 0, stream>>>(pts, ws);
    dim3 gridF(NPTS / 256, B);
    pm_final<<<gridF, 256, 0, stream>>>(pts, ws, out, 1.0f / (float)(B * NPTS));
}

// Round 3
// 95.228 us; speedup vs baseline: 1.2446x; 1.0239x over previous
//
#include <hip/hip_runtime.h>

#define NPTS 2048
#define QC 32                   // gt chunks per sample
#define G  (NPTS / QC)          // 64 gt points per chunk
#define RP 8                    // pred points per thread in pm_partial / pm_rotate
#define HARD_COS 0.9914448613738104f  // cos(7.5 deg); ang>15deg <=> clipped |dot| < this
#define META_FLOATS 24
#define PRED_OFF 1024           // float offset of pred_rot in ws (16B aligned)

// ws meta layout per sample (stride 24 floats): [0..8]=R_pred, [9..17]=R_gt,
// [18]=cls, [19]=valid, [20]=use_closest
// pred_rot: float4[B][NPTS] at PRED_OFF      {ppx,ppy,ppz,0}
// gt_rot:   float4[B][NPTS] at gt_off        {gx,gy,gz,|g|^2}
// cand:     float [B][QC][NPTS] at cand_off  best q index per chunk (as float)
__global__ void pm_prep(const float* __restrict__ pred,
                        const float* __restrict__ tgt,
                        const float* __restrict__ wgt,
                        const float* __restrict__ sym,
                        float* __restrict__ ws,
                        float* __restrict__ out,
                        int B, int C) {
    int b = blockIdx.x * blockDim.x + threadIdx.x;
    if (b == 0) out[0] = 0.0f;   // harness poisons d_out; final kernel atomically adds
    if (b >= B) return;

    int cls = 0; float valid = 0.0f;
    for (int c = 0; c < C; ++c) {
        if (wgt[b * 4 * C + c * 4] > 0.0f) { cls = c; valid = 1.0f; break; }
    }
    const float* qp = pred + b * 4 * C + cls * 4;
    const float* qg = tgt  + b * 4 * C + cls * 4;
    float pw = qp[0], px = qp[1], py = qp[2], pz = qp[3];
    float gw = qg[0], gx = qg[1], gy = qg[2], gz = qg[3];

    float* o = ws + (size_t)b * META_FLOATS;
    o[0] = 1.f - 2.f * (py * py + pz * pz);
    o[1] = 2.f * (px * py - pz * pw);
    o[2] = 2.f * (px * pz + py * pw);
    o[3] = 2.f * (px * py + pz * pw);
    o[4] = 1.f - 2.f * (px * px + pz * pz);
    o[5] = 2.f * (py * pz - px * pw);
    o[6] = 2.f * (px * pz - py * pw);
    o[7] = 2.f * (py * pz + px * pw);
    o[8] = 1.f - 2.f * (px * px + py * py);
    o[9]  = 1.f - 2.f * (gy * gy + gz * gz);
    o[10] = 2.f * (gx * gy - gz * gw);
    o[11] = 2.f * (gx * gz + gy * gw);
    o[12] = 2.f * (gx * gy + gz * gw);
    o[13] = 1.f - 2.f * (gx * gx + gz * gz);
    o[14] = 2.f * (gy * gz - gx * gw);
    o[15] = 2.f * (gx * gz - gy * gw);
    o[16] = 2.f * (gy * gz + gx * gw);
    o[17] = 1.f - 2.f * (gx * gx + gy * gy);

    float dot = fabsf(pw * gw + px * gx + py * gy + pz * gz);
    dot = fminf(fmaxf(dot, 0.0f), 1.0f);
    float uc = (sym[cls] > 0.0f && dot < HARD_COS) ? 1.0f : 0.0f;
    o[18] = (float)cls;
    o[19] = valid;
    o[20] = uc;
}

// grid (2, B): x=0 rotates pred cloud, x=1 rotates gt cloud (with |g|^2 in .w)
__global__ __launch_bounds__(256) void pm_rotate(const float* __restrict__ points,
                                                 float* __restrict__ ws,
                                                 int gt_off) {
    const int b = blockIdx.y;
    const int side = blockIdx.x;
    const float* o = ws + (size_t)b * META_FLOATS;
    if (o[19] == 0.0f) return;
    const int mbase = (side == 0) ? 0 : 9;
    const float m0 = o[mbase + 0], m1 = o[mbase + 1], m2 = o[mbase + 2],
                m3 = o[mbase + 3], m4 = o[mbase + 4], m5 = o[mbase + 5],
                m6 = o[mbase + 6], m7 = o[mbase + 7], m8 = o[mbase + 8];
    const int cls = (int)o[18];
    const float* pts = points + (size_t)cls * NPTS * 3;
    float4* dst = (float4*)(ws + (side == 0 ? PRED_OFF : gt_off)) + (size_t)b * NPTS;
    const int tid = threadIdx.x;
#pragma unroll
    for (int r = 0; r < RP; ++r) {
        int i = r * 256 + tid;
        float x = pts[i * 3 + 0], y = pts[i * 3 + 1], z = pts[i * 3 + 2];
        float ax = m0 * x + m1 * y + m2 * z;
        float ay = m3 * x + m4 * y + m5 * z;
        float az = m6 * x + m7 * y + m8 * z;
        float w = (side == 0) ? 0.0f : (ax * ax + ay * ay + az * az);
        dst[i] = make_float4(ax, ay, az, w);
    }
}

// grid (QC, B): each block scans one gt-chunk (G points) against ALL preds,
// RP preds per thread. Writes per-chunk argmin index to cand[b][qc][p].
__global__ __launch_bounds__(256) void pm_partial(float* __restrict__ ws,
                                                  int gt_off, int cand_off) {
    const int b  = blockIdx.y;
    const int qc = blockIdx.x;
    const float* o = ws + (size_t)b * META_FLOATS;
    if (o[19] == 0.0f || o[20] == 0.0f) return;   // !valid or !use_closest

    const float4* pred_rot = (const float4*)(ws + PRED_OFF) + (size_t)b * NPTS;
    const float4* gt_rot   = (const float4*)(ws + gt_off)   + (size_t)b * NPTS;
    const int tid = threadIdx.x;

    __shared__ float4 gt[G];
    if (tid < G) gt[tid] = gt_rot[qc * G + tid];
    __syncthreads();

    float nx[RP], ny[RP], nz[RP], bd[RP];
    int bi[RP];
#pragma unroll
    for (int r = 0; r < RP; ++r) {
        float4 pp = pred_rot[r * 256 + tid];
        nx[r] = -2.0f * pp.x; ny[r] = -2.0f * pp.y; nz[r] = -2.0f * pp.z;
        bd[r] = 3.4e38f; bi[r] = 0;
    }

#pragma unroll 4
    for (int j = 0; j < G; ++j) {
        float4 g = gt[j];
#pragma unroll
        for (int r = 0; r < RP; ++r) {
            float d = __fmaf_rn(nx[r], g.x,
                      __fmaf_rn(ny[r], g.y,
                      __fmaf_rn(nz[r], g.z, g.w)));
            if (d < bd[r]) { bd[r] = d; bi[r] = j; }   // strict <: first min
        }
    }

    float* cand = ws + cand_off + ((size_t)b * QC + qc) * NPTS;
#pragma unroll
    for (int r = 0; r < RP; ++r) {
        int p = r * 256 + tid;
        cand[p] = (float)(qc * G + bi[r]);     // coalesced
    }
}

__device__ __forceinline__ float smooth_l1(float x) {
    float ax = fabsf(x);
    return (ax < 1.0f) ? 0.5f * x * x : ax - 0.5f;
}

// grid (NPTS/256, B): resolve QC chunk winners per pred, smooth-L1, reduce.
__global__ __launch_bounds__(256) void pm_final(float* __restrict__ ws,
                                                float* __restrict__ out,
                                                int gt_off, int cand_off,
                                                float inv_bp) {
    __shared__ float partial[4];
    const int b = blockIdx.y;
    const float* o = ws + (size_t)b * META_FLOATS;
    const int tid = threadIdx.x;
    float acc = 0.0f;

    if (o[19] != 0.0f) {
        const float4* pred_rot = (const float4*)(ws + PRED_OFF) + (size_t)b * NPTS;
        const float4* gt_rot   = (const float4*)(ws + gt_off)   + (size_t)b * NPTS;
        const int p = blockIdx.x * 256 + tid;
        float4 pp = pred_rot[p];
        float mx, my, mz;
        if (o[20] != 0.0f) {
            const float nx = -2.0f * pp.x, ny = -2.0f * pp.y, nz = -2.0f * pp.z;
            const float* cand = ws + cand_off + (size_t)b * QC * NPTS + p;
            float bd = 3.4e38f; int bq = 0;
#pragma unroll 8
            for (int qc = 0; qc < QC; ++qc) {
                int q = (int)cand[(size_t)qc * NPTS];   // coalesced per qc
                float4 g = gt_rot[q];
                float d = __fmaf_rn(nx, g.x,
                          __fmaf_rn(ny, g.y,
                          __fmaf_rn(nz, g.z, g.w)));
                // candidates ascend in q with qc; strict < keeps global first-min
                if (d < bd) { bd = d; bq = q; }
            }
            float4 g = gt_rot[bq];
            mx = g.x; my = g.y; mz = g.z;
        } else {
            float4 g = gt_rot[p];
            mx = g.x; my = g.y; mz = g.z;
        }
        acc = smooth_l1(pp.x - mx) + smooth_l1(pp.y - my) + smooth_l1(pp.z - mz);
    }

    for (int off = 32; off > 0; off >>= 1) acc += __shfl_down(acc, off);
    if ((tid & 63) == 0) partial[tid >> 6] = acc;
    __syncthreads();
    if (tid == 0) {
        float s = partial[0] + partial[1] + partial[2] + partial[3];
        atomicAdd(out, s * inv_bp);
    }
}

extern "C" void kernel_launch(void* const* d_in, const int* in_sizes, int n_in,
                              void* d_out, int out_size, void* d_ws, size_t ws_size,
                              hipStream_t stream) {
    const float* pred = (const float*)d_in[0];
    const float* tgt  = (const float*)d_in[1];
    const float* wgt  = (const float*)d_in[2];
    const float* pts  = (const float*)d_in[3];
    const float* sym  = (const float*)d_in[4];
    float* out = (float*)d_out;
    float* ws  = (float*)d_ws;

    const int C = in_sizes[4];
    const int B = in_sizes[0] / (4 * C);

    const int gt_off   = PRED_OFF + B * NPTS * 4;            // floats
    const int cand_off = gt_off   + B * NPTS * 4;            // floats

    pm_prep<<<1, 64, 0, stream>>>(pred, tgt, wgt, sym, ws, out, B, C);
    dim3 gridR(2, B);
    pm_rotate<<<gridR, 256, 0, stream>>>(pts, ws, gt_off);
    dim3 gridP(QC, B);
    pm_partial<<<gridP, 256, 0, stream>>>(ws, gt_off, cand_off);
    dim3 gridF(NPTS / 256, B);
    pm_final<<<gridF, 256, 0, stream>>>(ws, out, gt_off, cand_off,
                                        1.0f / (float)(B * NPTS));
}